// Round 22
// baseline (711.955 us; speedup 1.0000x reference)
//
#include <hip/hip_runtime.h>
#include <hip/hip_bf16.h>
#include <math.h>
#include <string.h>

#define B_   16
#define S1_  61
#define S_   3721
#define D_   128
#define H_   8
#define NW_  61
#define FF_  512
#define BS_  (B_*S_)   // 59536

#define SC_LOG2E 0.36067376022224085f   // 0.25 * log2(e), folded into Q at the QKV GEMM

typedef unsigned int   uint32;
typedef unsigned short ushort16;
typedef __attribute__((ext_vector_type(8))) short  short8;
typedef __attribute__((ext_vector_type(4))) float  floatx4;
typedef __attribute__((ext_vector_type(4))) uint32 uint32x4;

__device__ __forceinline__ ushort16 f2bf(float f) {
  uint32 u = __float_as_uint(f);
  uint32 r = u + 0x7fffu + ((u >> 16) & 1u);   // RNE
  return (ushort16)(r >> 16);
}
__device__ __forceinline__ float bf2f(ushort16 s) {
  return __uint_as_float(((uint32)s) << 16);
}
__device__ __forceinline__ uint32 pkbf(float a, float b) {  // lo=bf16(a), hi=bf16(b) via v_cvt_pk_bf16_f32
  __hip_bfloat162 t = __float22bfloat162_rn(float2{a, b});
  uint32 r;
  memcpy(&r, &t, 4);
  return r;
}
__device__ __forceinline__ short8 mk8(uint32 a, uint32 b) {   // elements 0..3 = a,b; 4..7 = 0
  uint32x4 v = {a, b, 0u, 0u};
  return __builtin_bit_cast(short8, v);
}
// async global->LDS, 16B per lane; LDS dest = base + lane*16 (wave-uniform base)
__device__ __forceinline__ void gl2lds16(const void* g, void* l) {
  __builtin_amdgcn_global_load_lds(
      (const __attribute__((address_space(1))) unsigned int*)g,
      (__attribute__((address_space(3))) unsigned int*)l, 16, 0, 0);
}

// ---------------- weight prep: fp32 -> bf16, transposed to [N][K] ----------------
__global__ __launch_bounds__(256) void prep_w(
    const float* __restrict__ wq, const float* __restrict__ wk, const float* __restrict__ wv,
    const float* __restrict__ wo, const float* __restrict__ w1, const float* __restrict__ w2,
    const float* __restrict__ lt, const float* __restrict__ pw1,
    const float* __restrict__ cw, const float* __restrict__ cb,
    ushort16* __restrict__ qkv_t, ushort16* __restrict__ wo_t, ushort16* __restrict__ w1_t,
    ushort16* __restrict__ w2_t, ushort16* __restrict__ lt_t, ushort16* __restrict__ pw1_t,
    ushort16* __restrict__ wc_t, float* __restrict__ cb_pad) {
  int i = blockIdx.x * 256 + threadIdx.x;
  if (i < 196608) {                       // qkv: [l][n(384)][k(128)]
    int l = i / 49152, r = i % 49152;
    int n = r / 128, k = r % 128;
    const float* src = (n < 128) ? wq : (n < 256) ? wk : wv;
    qkv_t[i] = f2bf(src[(l * 128 + k) * 128 + (n & 127)]);
  } else if (i < 262144) {                // wo: [l][n][k]
    int j = i - 196608;
    int l = j / 16384, r = j % 16384;
    int n = r / 128, k = r % 128;
    wo_t[j] = f2bf(wo[(l * 128 + k) * 128 + n]);
  } else if (i < 524288) {                // w1: [l][n(512)][k(128)]
    int j = i - 262144;
    int l = j / 65536, r = j % 65536;
    int n = r / 128, k = r % 128;
    w1_t[j] = f2bf(w1[(size_t)l * 65536 + k * 512 + n]);
  } else if (i < 786432) {                // w2: [l][n(128)][k(512)]
    int j = i - 524288;
    int l = j / 65536, r = j % 65536;
    int n = r / 512, k = r % 512;
    w2_t[j] = f2bf(w2[(size_t)l * 65536 + k * 128 + n]);
  } else if (i < 794624) {                // lt: [n(128)][k(64 padded from 49)]
    int j = i - 786432;
    int n = j / 64, k = j % 64;
    lt_t[j] = f2bf(k < 49 ? lt[k * 128 + n] : 0.f);
  } else if (i < 811008) {                // pre_w1: [n][k]
    int j = i - 794624;
    int n = j / 128, k = j % 128;
    pw1_t[j] = f2bf(pw1[k * 128 + n]);
  } else if (i < 815104) {                // conv w: [c(64)][tap(64)], zero-padded
    int j = i - 811008;
    int n = j >> 6, k = j & 63;
    wc_t[j] = f2bf((n < 49 && k < 49) ? cw[n * 49 + k] : 0.f);
  } else if (i < 815168) {                // padded conv bias (64 floats)
    int j = i - 815104;
    cb_pad[j] = (j < 49) ? cb[j] : 0.f;
  }
}

// ---------------- im2col: x [B,61,61] fp32 -> X [BS][64] bf16 (taps, zero pad) ----
__global__ __launch_bounds__(256) void im2col_k(const float* __restrict__ x,
                                                ushort16* __restrict__ X) {
  int t = blockIdx.x * 256 + threadIdx.x;
  if (t >= BS_ * 64) return;
  int tap = t & 63;
  int row = t >> 6;
  if (tap >= 49) { X[t] = 0; return; }
  int b = row / S_, s = row % S_;
  int i = s / S1_, j = s % S1_;
  int di = tap / 7, dj = tap % 7;
  int ii = i + di - 3, jj = j + dj - 3;
  float v = 0.f;
  if ((unsigned)ii < (unsigned)S1_ && (unsigned)jj < (unsigned)S1_)
    v = x[(b * S1_ + ii) * S1_ + jj];
  X[t] = f2bf(v);
}

// ---------------- bf16 MFMA GEMM: C[M x N] = A[M x K] * Bt[N x K]^T ----------------
// 128x128 tile, 512 thr = 8 waves (32x64 quadrant each). K<=128: ALL K staged up
// front ((K/64)*32 KB LDS, ONE barrier; at 512 thr this keeps 16 waves/CU — the
// condition R11 lacked). K=512: BK=64 loop, trailing barrier skipped.
enum { E_BF16 = 0, E_H0LN = 1, E_RESLN = 2, E_GELU = 3, E_RELU = 4, E_RESBF = 5,
       E_QKV = 6, E_HEAD = 7 };

template <int EPI, int K>
__global__ __launch_bounds__(512) void gemm_bf16(
    const ushort16* __restrict__ A, int lda,
    const ushort16* __restrict__ Bt, int ldbt,
    ushort16* __restrict__ Hb,      // bf16 residual stream
    ushort16* __restrict__ Cb, int ldc,
    const float* __restrict__ bias,
    const float* __restrict__ pos,
    const float* __restrict__ ls,   // LN scale (E_*LN) / w2 (E_HEAD)
    const float* __restrict__ lb,   // LN bias  (E_*LN) / b2 (E_HEAD)
    float* __restrict__ Fout,       // head output (E_HEAD)
    int M, int N) {
  constexpr int NST = (K <= 128) ? (K / 64) : 1;
  __shared__ ushort16 As[NST * 8192];   // [stage][128 rows][64 ushorts], swizzled
  __shared__ ushort16 Bs[NST * 8192];
  __shared__ float stats[128][2][2];    // [row][col-half][s1,s2]
  int bm = blockIdx.y * 128, bn = blockIdx.x * 128;
  int tid = threadIdx.x;
  int lane = tid & 63, wave = tid >> 6;     // wave 0..7
  int wm = (wave >> 1) * 32, wn = (wave & 1) * 64;
  int ln = lane & 15, qd = lane >> 4;
  int lr = lane >> 3;                 // row within 8-row segment
  int cg = (lane & 7) ^ lr;           // swizzled global chunk index

  const ushort16* aP[2];
  const ushort16* bP[2];
  #pragma unroll
  for (int u = 0; u < 2; u++) {
    int s = wave * 2 + u;             // 16 segments of 8 rows
    int ar = bm + s * 8 + lr; if (ar > M - 1) ar = M - 1;
    int br = bn + s * 8 + lr; if (br > N - 1) br = N - 1;
    aP[u] = A  + (size_t)ar * lda  + cg * 8;
    bP[u] = Bt + (size_t)br * ldbt + cg * 8;
  }

  floatx4 acc[2][4] = {};
  if (K <= 128) {
    #pragma unroll
    for (int st = 0; st < NST; st++)
      #pragma unroll
      for (int u = 0; u < 2; u++) {
        int s = wave * 2 + u;
        gl2lds16(aP[u] + st * 64, &As[st * 8192 + s * 512]);
        gl2lds16(bP[u] + st * 64, &Bs[st * 8192 + s * 512]);
      }
    __syncthreads();
    #pragma unroll
    for (int st = 0; st < NST; st++) {
      #pragma unroll
      for (int ks = 0; ks < 64; ks += 32) {
        int cb0 = ks >> 3;
        short8 af[2], bf[4];
        #pragma unroll
        for (int i = 0; i < 2; i++) {
          int row = wm + i * 16 + ln;
          af[i] = *(const short8*)&As[st * 8192 + row * 64 + (((cb0 + qd) ^ (ln & 7)) * 8)];
        }
        #pragma unroll
        for (int j = 0; j < 4; j++) {
          int row = wn + j * 16 + ln;
          bf[j] = *(const short8*)&Bs[st * 8192 + row * 64 + (((cb0 + qd) ^ (ln & 7)) * 8)];
        }
        #pragma unroll
        for (int i = 0; i < 2; i++)
          #pragma unroll
          for (int j = 0; j < 4; j++)
            acc[i][j] = __builtin_amdgcn_mfma_f32_16x16x32_bf16(af[i], bf[j], acc[i][j], 0, 0, 0);
      }
    }
  } else {
    #pragma unroll
    for (int kc = 0; kc < K; kc += 64) {
      #pragma unroll
      for (int u = 0; u < 2; u++) {
        int s = wave * 2 + u;
        gl2lds16(aP[u] + kc, &As[s * 512]);
        gl2lds16(bP[u] + kc, &Bs[s * 512]);
      }
      __syncthreads();
      #pragma unroll
      for (int ks = 0; ks < 64; ks += 32) {
        int cb0 = ks >> 3;
        short8 af[2], bf[4];
        #pragma unroll
        for (int i = 0; i < 2; i++) {
          int row = wm + i * 16 + ln;
          af[i] = *(const short8*)&As[row * 64 + (((cb0 + qd) ^ (ln & 7)) * 8)];
        }
        #pragma unroll
        for (int j = 0; j < 4; j++) {
          int row = wn + j * 16 + ln;
          bf[j] = *(const short8*)&Bs[row * 64 + (((cb0 + qd) ^ (ln & 7)) * 8)];
        }
        #pragma unroll
        for (int i = 0; i < 2; i++)
          #pragma unroll
          for (int j = 0; j < 4; j++)
            acc[i][j] = __builtin_amdgcn_mfma_f32_16x16x32_bf16(af[i], bf[j], acc[i][j], 0, 0, 0);
      }
      if (kc + 64 < K) __syncthreads();   // no trailing drain on last iter
    }
  }

  if (EPI == E_H0LN || EPI == E_RESLN || EPI == E_RESBF) {
    // ---- residual/bias (+ optional fused LN) over full 128-wide rows (bn==0) ----
    float lsv[4], lbv[4];
    if (EPI != E_RESBF) {
      #pragma unroll
      for (int j = 0; j < 4; j++) {
        int gn = wn + j * 16 + ln;
        lsv[j] = ls[gn]; lbv[j] = lb[gn];
      }
    }
    int wI = wn >> 6;
    #pragma unroll
    for (int i = 0; i < 2; i++) {
      #pragma unroll
      for (int r = 0; r < 4; r++) {
        int lrow = wm + i * 16 + qd * 4 + r;
        int gm = bm + lrow;
        int gmc = (gm < M) ? gm : (M - 1);     // clamp reads (stores still guarded)
        float s1 = 0.f, s2 = 0.f;
        #pragma unroll
        for (int j = 0; j < 4; j++) {
          int gn = wn + j * 16 + ln;
          float v = acc[i][j][r];
          float g;
          if (EPI == E_H0LN) g = v + bias[gn] + pos[(size_t)(gmc % S_) * 128 + gn];
          else               g = bf2f(Hb[(size_t)gmc * 128 + gn]) + v + bias[gn];
          acc[i][j][r] = g;
          if (gm < M) Hb[(size_t)gm * 128 + gn] = f2bf(g);
          s1 += g; s2 = fmaf(g, g, s2);
        }
        if (EPI != E_RESBF) {
          #pragma unroll
          for (int off = 1; off <= 8; off <<= 1) {
            s1 += __shfl_xor(s1, off);
            s2 += __shfl_xor(s2, off);
          }
          if (ln == 0) { stats[lrow][wI][0] = s1; stats[lrow][wI][1] = s2; }
        }
      }
    }
    if (EPI != E_RESBF) {
      __syncthreads();
      #pragma unroll
      for (int i = 0; i < 2; i++) {
        #pragma unroll
        for (int r = 0; r < 4; r++) {
          int lrow = wm + i * 16 + qd * 4 + r;
          int gm = bm + lrow;
          if (gm >= M) continue;
          float s1 = stats[lrow][0][0] + stats[lrow][1][0];
          float s2 = stats[lrow][0][1] + stats[lrow][1][1];
          float mean = s1 * (1.f / 128.f);
          float var  = s2 * (1.f / 128.f) - mean * mean;
          float inv  = rsqrtf(fmaxf(var, 0.f) + 1e-5f);
          #pragma unroll
          for (int j = 0; j < 4; j++) {
            int gn = wn + j * 16 + ln;
            Cb[(size_t)gm * 128 + gn] = f2bf((acc[i][j][r] - mean) * inv * lsv[j] + lbv[j]);
          }
        }
      }
    }
  } else if (EPI == E_HEAD) {
    // ---- fused head: out[row] = sum_gn relu(v + b1[gn]) * w2[gn] + b2 ----
    float w2v[4];
    #pragma unroll
    for (int j = 0; j < 4; j++) {
      int gn = wn + j * 16 + ln;
      w2v[j] = ls[gn];
    }
    int wI = wn >> 6;
    #pragma unroll
    for (int i = 0; i < 2; i++) {
      #pragma unroll
      for (int r = 0; r < 4; r++) {
        int lrow = wm + i * 16 + qd * 4 + r;
        float s1 = 0.f;
        #pragma unroll
        for (int j = 0; j < 4; j++) {
          int gn = wn + j * 16 + ln;
          s1 = fmaf(fmaxf(acc[i][j][r] + bias[gn], 0.f), w2v[j], s1);
        }
        #pragma unroll
        for (int off = 1; off <= 8; off <<= 1) s1 += __shfl_xor(s1, off);
        if (ln == 0) stats[lrow][wI][0] = s1;
      }
    }
    __syncthreads();
    #pragma unroll
    for (int i = 0; i < 2; i++) {
      #pragma unroll
      for (int r = 0; r < 4; r++) {
        int lrow = wm + i * 16 + qd * 4 + r;
        int gm = bm + lrow;
        if (gm < M && ln == 0 && wI == 0)
          Fout[gm] = stats[lrow][0][0] + stats[lrow][1][0] + lb[0];
      }
    }
  } else {
    float qsc = (EPI == E_QKV && bn == 0) ? SC_LOG2E : 1.0f;   // wave-uniform
    #pragma unroll
    for (int i = 0; i < 2; i++) {
      #pragma unroll
      for (int r = 0; r < 4; r++) {
        int gm = bm + wm + i * 16 + qd * 4 + r;
        if (gm >= M) continue;
        #pragma unroll
        for (int j = 0; j < 4; j++) {
          int gn = bn + wn + j * 16 + ln;
          if (gn >= N) continue;
          float v = acc[i][j][r];
          if (EPI == E_BF16) {
            Cb[(size_t)gm * ldc + gn] = f2bf(v);
          } else if (EPI == E_QKV) {
            Cb[(size_t)gm * ldc + gn] = f2bf(v * qsc);
          } else if (EPI == E_GELU) {
            float g = v + bias[gn];
            g = 0.5f * g * (1.f + erff(g * 0.70710678118654752f));
            Cb[(size_t)gm * ldc + gn] = f2bf(g);
          } else if (EPI == E_RELU) {
            float g = fmaxf(v + bias[gn], 0.f);
            Cb[(size_t)gm * ldc + gn] = f2bf(g);
          }
        }
      }
    }
  }
}

// ---------------- MFMA windowed attention v6: 4 windows per 256-thr block -------
__global__ __launch_bounds__(256) void attn4(const ushort16* __restrict__ qkv,
                                             ushort16* __restrict__ o) {
  int bid = blockIdx.x;
  int xcd = bid & 7, idx = bid >> 3;        // 2048 = 8 * (16 bh) * (16 groups)
  int bh = xcd * 16 + (idx >> 4);           // XCD owns 16 (b,h) pairs
  int wg = idx & 15;
  int hh = bh & 7, b = bh >> 3;
  __shared__ ushort16 Kl[384][16];          // rows base..base+383 (366 used)
  __shared__ ushort16 Vl[384][16];
  int tid = threadIdx.x;
  int lane = tid & 63, wave = tid >> 6;     // wave 0..3
  int qcol = lane & 15, quad = lane >> 4;
  int w0 = wg * 4;
  int w  = w0 + wave;                       // 60..63 in last group: clamped below
  int base = (w0 - 1) * 61;

  // cooperative staging: 12 chunks (wave v does chunks 3v..3v+2), rows clamped
  #pragma unroll
  for (int cc = 0; cc < 3; cc++) {
    int c = wave * 3 + cc;
    int e = c * 64 + lane;
    int row = e >> 1, half = (e & 1) * 8;
    int krow = base + row;
    if (krow < 0) krow = 0;
    if (krow > S_ - 1) krow = S_ - 1;       // clamped rows masked later
    const ushort16* gk = qkv + ((size_t)(b * S_ + krow) * 384 + 128 + hh * 16 + half);
    gl2lds16(gk,       &Kl[0][0] + c * 512);
    gl2lds16(gk + 128, &Vl[0][0] + c * 512);
  }

  int qw = (w > 60) ? 60 : w;
  short8 qf[4];
  #pragma unroll
  for (int qt = 0; qt < 4; qt++) {
    int qloc = qt * 16 + qcol;
    if (qloc > 60) qloc = 60;               // clamped lanes never stored
    const uint32* qp = (const uint32*)(qkv + ((size_t)(b * S_ + qw * 61 + qloc) * 384 + hh * 16 + quad * 4));
    qf[qt] = mk8(qp[0], qp[1]);
  }
  __syncthreads();

  int woff = wave * 61;                     // this wave's window starts at local row woff
  int j0 = (w == 0) ? 61 : 0;
  int j1 = (w >= 60) ? 122 : 183;
  int kt0 = (w == 0) ? 3 : 0;
  int kt1 = (w == 60) ? 8 : ((w > 60) ? 0 : 12);

  floatx4 oacc[4];
  #pragma unroll
  for (int qt = 0; qt < 4; qt++) { oacc[qt][0]=0.f; oacc[qt][1]=0.f; oacc[qt][2]=0.f; oacc[qt][3]=0.f; }
  float lsum[4] = {0.f, 0.f, 0.f, 0.f};
  const floatx4 zero4 = {0.f, 0.f, 0.f, 0.f};

  for (int kt = kt0; kt < kt1; kt++) {
    const uint32* kp = (const uint32*)&Kl[woff + kt * 16 + qcol][quad * 4];
    short8 kf = mk8(kp[0], kp[1]);

    int kb = kt * 16 + quad * 4;
    uint32 va = (uint32)Vl[woff + kb + 0][qcol] | ((uint32)Vl[woff + kb + 1][qcol] << 16);
    uint32 vb = (uint32)Vl[woff + kb + 2][qcol] | ((uint32)Vl[woff + kb + 3][qcol] << 16);
    short8 vf = mk8(va, vb);

    floatx4 sacc[4];
    #pragma unroll
    for (int qt = 0; qt < 4; qt++)
      sacc[qt] = __builtin_amdgcn_mfma_f32_16x16x32_bf16(kf, qf[qt], zero4, 0, 0, 0);

    uint32 m01 = (((unsigned)(kb + 0 - j0) < (unsigned)(j1 - j0)) ? 0x0000ffffu : 0u)
               | (((unsigned)(kb + 1 - j0) < (unsigned)(j1 - j0)) ? 0xffff0000u : 0u);
    uint32 m23 = (((unsigned)(kb + 2 - j0) < (unsigned)(j1 - j0)) ? 0x0000ffffu : 0u)
               | (((unsigned)(kb + 3 - j0) < (unsigned)(j1 - j0)) ? 0xffff0000u : 0u);
    #pragma unroll
    for (int qt = 0; qt < 4; qt++) {
      float e0 = __builtin_amdgcn_exp2f(sacc[qt][0]);
      float e1 = __builtin_amdgcn_exp2f(sacc[qt][1]);
      float e2 = __builtin_amdgcn_exp2f(sacc[qt][2]);
      float e3 = __builtin_amdgcn_exp2f(sacc[qt][3]);
      uint32 p01 = pkbf(e0, e1) & m01;
      uint32 p23 = pkbf(e2, e3) & m23;
      lsum[qt] += (__uint_as_float(p01 << 16) + __uint_as_float(p01 & 0xffff0000u))
                + (__uint_as_float(p23 << 16) + __uint_as_float(p23 & 0xffff0000u));
      oacc[qt] = __builtin_amdgcn_mfma_f32_16x16x32_bf16(mk8(p01, p23), vf, oacc[qt], 0, 0, 0);
    }
  }

  #pragma unroll
  for (int qt = 0; qt < 4; qt++) {
    float l = lsum[qt];
    l += __shfl_xor(l, 16);
    l += __shfl_xor(l, 32);
    lsum[qt] = 1.0f / fmaxf(l, 1e-30f);
  }
  if (w <= 60) {
    #pragma unroll
    for (int qt = 0; qt < 4; qt++) {
      #pragma unroll
      for (int r = 0; r < 4; r++) {
        int qloc = qt * 16 + quad * 4 + r;
        float invl = __shfl(lsum[qt], quad * 4 + r);
        if (qloc < 61) {
          size_t row = (size_t)b * S_ + w * 61 + qloc;
          o[row * 128 + hh * 16 + qcol] = f2bf(oacc[qt][r] * invl);
        }
      }
    }
  }
}

extern "C" void kernel_launch(void* const* d_in, const int* in_sizes, int n_in,
                              void* d_out, int out_size, void* d_ws, size_t ws_size,
                              hipStream_t stream) {
  const float* x      = (const float*)d_in[0];
  const float* conv_w = (const float*)d_in[1];
  const float* conv_b = (const float*)d_in[2];
  const float* lt_w   = (const float*)d_in[3];
  const float* lt_b   = (const float*)d_in[4];
  const float* pos    = (const float*)d_in[5];
  const float* ln1_s  = (const float*)d_in[6];
  const float* ln1_b  = (const float*)d_in[7];
  const float* wq     = (const float*)d_in[8];
  const float* wk     = (const float*)d_in[9];
  const float* wv     = (const float*)d_in[10];
  const float* wo     = (const float*)d_in[11];
  const float* wo_b   = (const float*)d_in[12];
  const float* ln2_s  = (const float*)d_in[13];
  const float* ln2_b  = (const float*)d_in[14];
  const float* ff_w1  = (const float*)d_in[15];
  const float* ff_b1  = (const float*)d_in[16];
  const float* ff_w2  = (const float*)d_in[17];
  const float* ff_b2  = (const float*)d_in[18];
  const float* pre_w1 = (const float*)d_in[19];
  const float* pre_b1 = (const float*)d_in[20];
  const float* pre_w2 = (const float*)d_in[21];
  const float* pre_b2 = (const float*)d_in[22];

  char* ws = (char*)d_ws;
  const size_t SZ_HB  = (size_t)BS_ * 128 * 2;   // bf16 residual stream
  const size_t SZ_QKV = (size_t)BS_ * 384 * 2;
  const size_t SZ_O   = (size_t)BS_ * 128 * 2;
  ushort16* h    = (ushort16*)ws;
  ushort16* hn   = (ushort16*)(ws + SZ_HB);
  ushort16* qkvb = (ushort16*)(ws + 2 * SZ_HB);                 // also p, t
  ushort16* ob   = (ushort16*)(ws + 2 * SZ_HB + SZ_QKV);        // also X
  char*     wsw  = ws + 2 * SZ_HB + SZ_QKV + SZ_O;
  ushort16* qkv_t = (ushort16*)(wsw);
  ushort16* wo_t  = qkv_t + 196608;
  ushort16* w1_t  = wo_t  + 65536;
  ushort16* w2_t  = w1_t  + 262144;
  ushort16* lt_t  = w2_t  + 262144;
  ushort16* pw1_t = lt_t  + 8192;
  ushort16* wc_t  = pw1_t + 16384;
  float*    cb_pad = (float*)(wc_t + 4096);
  ushort16* X  = ob;        // im2col patches [BS][64] bf16
  ushort16* p  = qkvb;      // conv output (post-relu) [BS][64] bf16
  ushort16* t  = qkvb;      // FF intermediate [BS][512]

  prep_w<<<dim3(3185), 256, 0, stream>>>(wq, wk, wv, wo, ff_w1, ff_w2, lt_w, pre_w1,
                                         conv_w, conv_b,
                                         qkv_t, wo_t, w1_t, w2_t, lt_t, pw1_t, wc_t, cb_pad);
  im2col_k<<<dim3((BS_ * 64 + 255) / 256), 256, 0, stream>>>(x, X);

  const int MB = (BS_ + 127) / 128;  // 466
  // p = relu(X @ Wc^T + cb)
  gemm_bf16<E_RELU, 64><<<dim3(1, MB), 512, 0, stream>>>(X, 64, wc_t, 64, nullptr, p, 64,
                                                         cb_pad, nullptr, nullptr, nullptr, nullptr,
                                                         BS_, 64);
  // h = p @ lt_w + lt_b + pos ; hn = LN1_0(h)
  gemm_bf16<E_H0LN, 64><<<dim3(1, MB), 512, 0, stream>>>(p, 64, lt_t, 64, h, hn, 128,
                                                         lt_b, pos, ln1_s, ln1_b, nullptr, BS_, 128);

  for (int l = 0; l < 4; l++) {
    gemm_bf16<E_QKV, 128><<<dim3(3, MB), 512, 0, stream>>>(hn, 128, qkv_t + (size_t)l * 49152, 128,
                                                           nullptr, qkvb, 384, nullptr, nullptr,
                                                           nullptr, nullptr, nullptr, BS_, 384);
    attn4<<<dim3(2048), 256, 0, stream>>>(qkvb, ob);
    // h += o @ wo + wo_b ; hn = LN2_l(h)
    gemm_bf16<E_RESLN, 128><<<dim3(1, MB), 512, 0, stream>>>(ob, 128, wo_t + (size_t)l * 16384, 128,
                                                             h, hn, 128, wo_b + l * 128, nullptr,
                                                             ln2_s + l * 128, ln2_b + l * 128, nullptr,
                                                             BS_, 128);
    gemm_bf16<E_GELU, 128><<<dim3(4, MB), 512, 0, stream>>>(hn, 128, w1_t + (size_t)l * 65536, 128,
                                                            nullptr, t, 512, ff_b1 + l * 512, nullptr,
                                                            nullptr, nullptr, nullptr, BS_, 512);
    if (l < 3) {
      // h += t @ w2 + b2 ; hn = LN1_{l+1}(h)
      gemm_bf16<E_RESLN, 512><<<dim3(1, MB), 512, 0, stream>>>(t, 512, w2_t + (size_t)l * 65536, 512,
                                                               h, hn, 128, ff_b2 + l * 128, nullptr,
                                                               ln1_s + (l + 1) * 128, ln1_b + (l + 1) * 128,
                                                               nullptr, BS_, 128);
    } else {  // final: h += t @ w2 + b2 (bf16 h, no LN)
      gemm_bf16<E_RESBF, 512><<<dim3(1, MB), 512, 0, stream>>>(t, 512, w2_t + (size_t)l * 65536, 512,
                                                               h, nullptr, 128, ff_b2 + l * 128, nullptr,
                                                               nullptr, nullptr, nullptr, BS_, 128);
    }
  }
  // fused head: out = relu(h @ pre_w1 + pre_b1) @ pre_w2 + pre_b2
  gemm_bf16<E_HEAD, 128><<<dim3(1, MB), 512, 0, stream>>>(h, 128, pw1_t, 128,
                                                          nullptr, nullptr, 128, pre_b1, nullptr,
                                                          pre_w2, pre_b2, (float*)d_out, BS_, 128);
}

// Round 23
// 661.032 us; speedup vs baseline: 1.0770x; 1.0770x over previous
//
#include <hip/hip_runtime.h>
#include <hip/hip_bf16.h>
#include <math.h>
#include <string.h>

#define B_   16
#define S1_  61
#define S_   3721
#define D_   128
#define H_   8
#define NW_  61
#define FF_  512
#define BS_  (B_*S_)   // 59536

#define SC_LOG2E 0.36067376022224085f   // 0.25 * log2(e), folded into Q at the QKV GEMM

typedef unsigned int   uint32;
typedef unsigned short ushort16;
typedef __attribute__((ext_vector_type(8))) short  short8;
typedef __attribute__((ext_vector_type(4))) float  floatx4;
typedef __attribute__((ext_vector_type(4))) uint32 uint32x4;

__device__ __forceinline__ ushort16 f2bf(float f) {
  uint32 u = __float_as_uint(f);
  uint32 r = u + 0x7fffu + ((u >> 16) & 1u);   // RNE
  return (ushort16)(r >> 16);
}
__device__ __forceinline__ float bf2f(ushort16 s) {
  return __uint_as_float(((uint32)s) << 16);
}
__device__ __forceinline__ uint32 pkbf(float a, float b) {  // lo=bf16(a), hi=bf16(b) via v_cvt_pk_bf16_f32
  __hip_bfloat162 t = __float22bfloat162_rn(float2{a, b});
  uint32 r;
  memcpy(&r, &t, 4);
  return r;
}
__device__ __forceinline__ short8 mk8(uint32 a, uint32 b) {   // elements 0..3 = a,b; 4..7 = 0
  uint32x4 v = {a, b, 0u, 0u};
  return __builtin_bit_cast(short8, v);
}
// async global->LDS, 16B per lane; LDS dest = base + lane*16 (wave-uniform base)
__device__ __forceinline__ void gl2lds16(const void* g, void* l) {
  __builtin_amdgcn_global_load_lds(
      (const __attribute__((address_space(1))) unsigned int*)g,
      (__attribute__((address_space(3))) unsigned int*)l, 16, 0, 0);
}

// ---------------- weight prep: fp32 -> bf16, transposed to [N][K] ----------------
__global__ __launch_bounds__(256) void prep_w(
    const float* __restrict__ wq, const float* __restrict__ wk, const float* __restrict__ wv,
    const float* __restrict__ wo, const float* __restrict__ w1, const float* __restrict__ w2,
    const float* __restrict__ lt, const float* __restrict__ pw1,
    const float* __restrict__ cw, const float* __restrict__ cb,
    ushort16* __restrict__ qkv_t, ushort16* __restrict__ wo_t, ushort16* __restrict__ w1_t,
    ushort16* __restrict__ w2_t, ushort16* __restrict__ lt_t, ushort16* __restrict__ pw1_t,
    ushort16* __restrict__ wc_t, float* __restrict__ cb_pad) {
  int i = blockIdx.x * 256 + threadIdx.x;
  if (i < 196608) {                       // qkv: [l][n(384)][k(128)]
    int l = i / 49152, r = i % 49152;
    int n = r / 128, k = r % 128;
    const float* src = (n < 128) ? wq : (n < 256) ? wk : wv;
    qkv_t[i] = f2bf(src[(l * 128 + k) * 128 + (n & 127)]);
  } else if (i < 262144) {                // wo: [l][n][k]
    int j = i - 196608;
    int l = j / 16384, r = j % 16384;
    int n = r / 128, k = r % 128;
    wo_t[j] = f2bf(wo[(l * 128 + k) * 128 + n]);
  } else if (i < 524288) {                // w1: [l][n(512)][k(128)]
    int j = i - 262144;
    int l = j / 65536, r = j % 65536;
    int n = r / 128, k = r % 128;
    w1_t[j] = f2bf(w1[(size_t)l * 65536 + k * 512 + n]);
  } else if (i < 786432) {                // w2: [l][n(128)][k(512)]
    int j = i - 524288;
    int l = j / 65536, r = j % 65536;
    int n = r / 512, k = r % 512;
    w2_t[j] = f2bf(w2[(size_t)l * 65536 + k * 128 + n]);
  } else if (i < 794624) {                // lt: [n(128)][k(64 padded from 49)]
    int j = i - 786432;
    int n = j / 64, k = j % 64;
    lt_t[j] = f2bf(k < 49 ? lt[k * 128 + n] : 0.f);
  } else if (i < 811008) {                // pre_w1: [n][k]
    int j = i - 794624;
    int n = j / 128, k = j % 128;
    pw1_t[j] = f2bf(pw1[k * 128 + n]);
  } else if (i < 815104) {                // conv w: [c(64)][tap(64)], zero-padded
    int j = i - 811008;
    int n = j >> 6, k = j & 63;
    wc_t[j] = f2bf((n < 49 && k < 49) ? cw[n * 49 + k] : 0.f);
  } else if (i < 815168) {                // padded conv bias (64 floats)
    int j = i - 815104;
    cb_pad[j] = (j < 49) ? cb[j] : 0.f;
  }
}

// ---------------- im2col: x [B,61,61] fp32 -> X [BS][64] bf16 (taps, zero pad) ----
__global__ __launch_bounds__(256) void im2col_k(const float* __restrict__ x,
                                                ushort16* __restrict__ X) {
  int t = blockIdx.x * 256 + threadIdx.x;
  if (t >= BS_ * 64) return;
  int tap = t & 63;
  int row = t >> 6;
  if (tap >= 49) { X[t] = 0; return; }
  int b = row / S_, s = row % S_;
  int i = s / S1_, j = s % S1_;
  int di = tap / 7, dj = tap % 7;
  int ii = i + di - 3, jj = j + dj - 3;
  float v = 0.f;
  if ((unsigned)ii < (unsigned)S1_ && (unsigned)jj < (unsigned)S1_)
    v = x[(b * S1_ + ii) * S1_ + jj];
  X[t] = f2bf(v);
}

// ---------------- bf16 MFMA GEMM: C[M x N] = A[M x K] * Bt[N x K]^T ----------------
// 128x128 tile, 512 thr = 8 waves (32x64 quadrant each).
// SB=true (E_QKV only, measured faster): ALL K staged up front, ONE barrier, 64 KB.
// SB=false: 32 KB BK=64 loop (best residency for small-grid kernels).
enum { E_BF16 = 0, E_H0LN = 1, E_RESLN = 2, E_GELU = 3, E_RELU = 4, E_RESBF = 5,
       E_QKV = 6, E_HEAD = 7 };

template <int EPI, int K, bool SB>
__global__ __launch_bounds__(512) void gemm_bf16(
    const ushort16* __restrict__ A, int lda,
    const ushort16* __restrict__ Bt, int ldbt,
    ushort16* __restrict__ Hb,      // bf16 residual stream
    ushort16* __restrict__ Cb, int ldc,
    const float* __restrict__ bias,
    const float* __restrict__ pos,
    const float* __restrict__ ls,   // LN scale (E_*LN) / w2 (E_HEAD)
    const float* __restrict__ lb,   // LN bias  (E_*LN) / b2 (E_HEAD)
    float* __restrict__ Fout,       // head output (E_HEAD)
    int M, int N) {
  constexpr int NST = (SB && K <= 128) ? (K / 64) : 1;
  __shared__ ushort16 As[NST * 8192];   // [stage][128 rows][64 ushorts], swizzled
  __shared__ ushort16 Bs[NST * 8192];
  __shared__ float stats[128][2][2];    // [row][col-half][s1,s2]
  int bm = blockIdx.y * 128, bn = blockIdx.x * 128;
  int tid = threadIdx.x;
  int lane = tid & 63, wave = tid >> 6;     // wave 0..7
  int wm = (wave >> 1) * 32, wn = (wave & 1) * 64;
  int ln = lane & 15, qd = lane >> 4;
  int lr = lane >> 3;                 // row within 8-row segment
  int cg = (lane & 7) ^ lr;           // swizzled global chunk index

  const ushort16* aP[2];
  const ushort16* bP[2];
  #pragma unroll
  for (int u = 0; u < 2; u++) {
    int s = wave * 2 + u;             // 16 segments of 8 rows
    int ar = bm + s * 8 + lr; if (ar > M - 1) ar = M - 1;
    int br = bn + s * 8 + lr; if (br > N - 1) br = N - 1;
    aP[u] = A  + (size_t)ar * lda  + cg * 8;
    bP[u] = Bt + (size_t)br * ldbt + cg * 8;
  }

  floatx4 acc[2][4] = {};
  if (SB && K <= 128) {
    #pragma unroll
    for (int st = 0; st < NST; st++)
      #pragma unroll
      for (int u = 0; u < 2; u++) {
        int s = wave * 2 + u;
        gl2lds16(aP[u] + st * 64, &As[st * 8192 + s * 512]);
        gl2lds16(bP[u] + st * 64, &Bs[st * 8192 + s * 512]);
      }
    __syncthreads();
    #pragma unroll
    for (int st = 0; st < NST; st++) {
      #pragma unroll
      for (int ks = 0; ks < 64; ks += 32) {
        int cb0 = ks >> 3;
        short8 af[2], bf[4];
        #pragma unroll
        for (int i = 0; i < 2; i++) {
          int row = wm + i * 16 + ln;
          af[i] = *(const short8*)&As[st * 8192 + row * 64 + (((cb0 + qd) ^ (ln & 7)) * 8)];
        }
        #pragma unroll
        for (int j = 0; j < 4; j++) {
          int row = wn + j * 16 + ln;
          bf[j] = *(const short8*)&Bs[st * 8192 + row * 64 + (((cb0 + qd) ^ (ln & 7)) * 8)];
        }
        #pragma unroll
        for (int i = 0; i < 2; i++)
          #pragma unroll
          for (int j = 0; j < 4; j++)
            acc[i][j] = __builtin_amdgcn_mfma_f32_16x16x32_bf16(af[i], bf[j], acc[i][j], 0, 0, 0);
      }
    }
  } else {
    #pragma unroll
    for (int kc = 0; kc < K; kc += 64) {
      #pragma unroll
      for (int u = 0; u < 2; u++) {
        int s = wave * 2 + u;
        gl2lds16(aP[u] + kc, &As[s * 512]);
        gl2lds16(bP[u] + kc, &Bs[s * 512]);
      }
      __syncthreads();
      #pragma unroll
      for (int ks = 0; ks < 64; ks += 32) {
        int cb0 = ks >> 3;
        short8 af[2], bf[4];
        #pragma unroll
        for (int i = 0; i < 2; i++) {
          int row = wm + i * 16 + ln;
          af[i] = *(const short8*)&As[row * 64 + (((cb0 + qd) ^ (ln & 7)) * 8)];
        }
        #pragma unroll
        for (int j = 0; j < 4; j++) {
          int row = wn + j * 16 + ln;
          bf[j] = *(const short8*)&Bs[row * 64 + (((cb0 + qd) ^ (ln & 7)) * 8)];
        }
        #pragma unroll
        for (int i = 0; i < 2; i++)
          #pragma unroll
          for (int j = 0; j < 4; j++)
            acc[i][j] = __builtin_amdgcn_mfma_f32_16x16x32_bf16(af[i], bf[j], acc[i][j], 0, 0, 0);
      }
      if (kc + 64 < K) __syncthreads();   // no trailing drain on last iter
    }
  }

  if (EPI == E_H0LN || EPI == E_RESLN || EPI == E_RESBF) {
    // ---- residual/bias (+ optional fused LN) over full 128-wide rows (bn==0) ----
    float lsv[4], lbv[4];
    if (EPI != E_RESBF) {
      #pragma unroll
      for (int j = 0; j < 4; j++) {
        int gn = wn + j * 16 + ln;
        lsv[j] = ls[gn]; lbv[j] = lb[gn];
      }
    }
    int wI = wn >> 6;
    #pragma unroll
    for (int i = 0; i < 2; i++) {
      #pragma unroll
      for (int r = 0; r < 4; r++) {
        int lrow = wm + i * 16 + qd * 4 + r;
        int gm = bm + lrow;
        int gmc = (gm < M) ? gm : (M - 1);     // clamp reads (stores still guarded)
        float s1 = 0.f, s2 = 0.f;
        #pragma unroll
        for (int j = 0; j < 4; j++) {
          int gn = wn + j * 16 + ln;
          float v = acc[i][j][r];
          float g;
          if (EPI == E_H0LN) g = v + bias[gn] + pos[(size_t)(gmc % S_) * 128 + gn];
          else               g = bf2f(Hb[(size_t)gmc * 128 + gn]) + v + bias[gn];
          acc[i][j][r] = g;
          if (gm < M) Hb[(size_t)gm * 128 + gn] = f2bf(g);
          s1 += g; s2 = fmaf(g, g, s2);
        }
        if (EPI != E_RESBF) {
          #pragma unroll
          for (int off = 1; off <= 8; off <<= 1) {
            s1 += __shfl_xor(s1, off);
            s2 += __shfl_xor(s2, off);
          }
          if (ln == 0) { stats[lrow][wI][0] = s1; stats[lrow][wI][1] = s2; }
        }
      }
    }
    if (EPI != E_RESBF) {
      __syncthreads();
      #pragma unroll
      for (int i = 0; i < 2; i++) {
        #pragma unroll
        for (int r = 0; r < 4; r++) {
          int lrow = wm + i * 16 + qd * 4 + r;
          int gm = bm + lrow;
          if (gm >= M) continue;
          float s1 = stats[lrow][0][0] + stats[lrow][1][0];
          float s2 = stats[lrow][0][1] + stats[lrow][1][1];
          float mean = s1 * (1.f / 128.f);
          float var  = s2 * (1.f / 128.f) - mean * mean;
          float inv  = rsqrtf(fmaxf(var, 0.f) + 1e-5f);
          #pragma unroll
          for (int j = 0; j < 4; j++) {
            int gn = wn + j * 16 + ln;
            Cb[(size_t)gm * 128 + gn] = f2bf((acc[i][j][r] - mean) * inv * lsv[j] + lbv[j]);
          }
        }
      }
    }
  } else if (EPI == E_HEAD) {
    // ---- fused head: out[row] = sum_gn relu(v + b1[gn]) * w2[gn] + b2 ----
    float w2v[4];
    #pragma unroll
    for (int j = 0; j < 4; j++) {
      int gn = wn + j * 16 + ln;
      w2v[j] = ls[gn];
    }
    int wI = wn >> 6;
    #pragma unroll
    for (int i = 0; i < 2; i++) {
      #pragma unroll
      for (int r = 0; r < 4; r++) {
        int lrow = wm + i * 16 + qd * 4 + r;
        float s1 = 0.f;
        #pragma unroll
        for (int j = 0; j < 4; j++) {
          int gn = wn + j * 16 + ln;
          s1 = fmaf(fmaxf(acc[i][j][r] + bias[gn], 0.f), w2v[j], s1);
        }
        #pragma unroll
        for (int off = 1; off <= 8; off <<= 1) s1 += __shfl_xor(s1, off);
        if (ln == 0) stats[lrow][wI][0] = s1;
      }
    }
    __syncthreads();
    #pragma unroll
    for (int i = 0; i < 2; i++) {
      #pragma unroll
      for (int r = 0; r < 4; r++) {
        int lrow = wm + i * 16 + qd * 4 + r;
        int gm = bm + lrow;
        if (gm < M && ln == 0 && wI == 0)
          Fout[gm] = stats[lrow][0][0] + stats[lrow][1][0] + lb[0];
      }
    }
  } else {
    float qsc = (EPI == E_QKV && bn == 0) ? SC_LOG2E : 1.0f;   // wave-uniform
    #pragma unroll
    for (int i = 0; i < 2; i++) {
      #pragma unroll
      for (int r = 0; r < 4; r++) {
        int gm = bm + wm + i * 16 + qd * 4 + r;
        if (gm >= M) continue;
        #pragma unroll
        for (int j = 0; j < 4; j++) {
          int gn = bn + wn + j * 16 + ln;
          if (gn >= N) continue;
          float v = acc[i][j][r];
          if (EPI == E_BF16) {
            Cb[(size_t)gm * ldc + gn] = f2bf(v);
          } else if (EPI == E_QKV) {
            Cb[(size_t)gm * ldc + gn] = f2bf(v * qsc);
          } else if (EPI == E_GELU) {
            float g = v + bias[gn];
            g = 0.5f * g * (1.f + erff(g * 0.70710678118654752f));
            Cb[(size_t)gm * ldc + gn] = f2bf(g);
          } else if (EPI == E_RELU) {
            float g = fmaxf(v + bias[gn], 0.f);
            Cb[(size_t)gm * ldc + gn] = f2bf(g);
          }
        }
      }
    }
  }
}

// ---------------- MFMA windowed attention v6: 4 windows per 256-thr block -------
__global__ __launch_bounds__(256) void attn4(const ushort16* __restrict__ qkv,
                                             ushort16* __restrict__ o) {
  int bid = blockIdx.x;
  int xcd = bid & 7, idx = bid >> 3;        // 2048 = 8 * (16 bh) * (16 groups)
  int bh = xcd * 16 + (idx >> 4);           // XCD owns 16 (b,h) pairs
  int wg = idx & 15;
  int hh = bh & 7, b = bh >> 3;
  __shared__ ushort16 Kl[384][16];          // rows base..base+383 (366 used)
  __shared__ ushort16 Vl[384][16];
  int tid = threadIdx.x;
  int lane = tid & 63, wave = tid >> 6;     // wave 0..3
  int qcol = lane & 15, quad = lane >> 4;
  int w0 = wg * 4;
  int w  = w0 + wave;                       // 60..63 in last group: clamped below
  int base = (w0 - 1) * 61;

  // cooperative staging: 12 chunks (wave v does chunks 3v..3v+2), rows clamped
  #pragma unroll
  for (int cc = 0; cc < 3; cc++) {
    int c = wave * 3 + cc;
    int e = c * 64 + lane;
    int row = e >> 1, half = (e & 1) * 8;
    int krow = base + row;
    if (krow < 0) krow = 0;
    if (krow > S_ - 1) krow = S_ - 1;       // clamped rows masked later
    const ushort16* gk = qkv + ((size_t)(b * S_ + krow) * 384 + 128 + hh * 16 + half);
    gl2lds16(gk,       &Kl[0][0] + c * 512);
    gl2lds16(gk + 128, &Vl[0][0] + c * 512);
  }

  int qw = (w > 60) ? 60 : w;
  short8 qf[4];
  #pragma unroll
  for (int qt = 0; qt < 4; qt++) {
    int qloc = qt * 16 + qcol;
    if (qloc > 60) qloc = 60;               // clamped lanes never stored
    const uint32* qp = (const uint32*)(qkv + ((size_t)(b * S_ + qw * 61 + qloc) * 384 + hh * 16 + quad * 4));
    qf[qt] = mk8(qp[0], qp[1]);
  }
  __syncthreads();

  int woff = wave * 61;                     // this wave's window starts at local row woff
  int j0 = (w == 0) ? 61 : 0;
  int j1 = (w >= 60) ? 122 : 183;
  int kt0 = (w == 0) ? 3 : 0;
  int kt1 = (w == 60) ? 8 : ((w > 60) ? 0 : 12);

  floatx4 oacc[4];
  #pragma unroll
  for (int qt = 0; qt < 4; qt++) { oacc[qt][0]=0.f; oacc[qt][1]=0.f; oacc[qt][2]=0.f; oacc[qt][3]=0.f; }
  float lsum[4] = {0.f, 0.f, 0.f, 0.f};
  const floatx4 zero4 = {0.f, 0.f, 0.f, 0.f};

  for (int kt = kt0; kt < kt1; kt++) {
    const uint32* kp = (const uint32*)&Kl[woff + kt * 16 + qcol][quad * 4];
    short8 kf = mk8(kp[0], kp[1]);

    int kb = kt * 16 + quad * 4;
    uint32 va = (uint32)Vl[woff + kb + 0][qcol] | ((uint32)Vl[woff + kb + 1][qcol] << 16);
    uint32 vb = (uint32)Vl[woff + kb + 2][qcol] | ((uint32)Vl[woff + kb + 3][qcol] << 16);
    short8 vf = mk8(va, vb);

    floatx4 sacc[4];
    #pragma unroll
    for (int qt = 0; qt < 4; qt++)
      sacc[qt] = __builtin_amdgcn_mfma_f32_16x16x32_bf16(kf, qf[qt], zero4, 0, 0, 0);

    uint32 m01 = (((unsigned)(kb + 0 - j0) < (unsigned)(j1 - j0)) ? 0x0000ffffu : 0u)
               | (((unsigned)(kb + 1 - j0) < (unsigned)(j1 - j0)) ? 0xffff0000u : 0u);
    uint32 m23 = (((unsigned)(kb + 2 - j0) < (unsigned)(j1 - j0)) ? 0x0000ffffu : 0u)
               | (((unsigned)(kb + 3 - j0) < (unsigned)(j1 - j0)) ? 0xffff0000u : 0u);
    #pragma unroll
    for (int qt = 0; qt < 4; qt++) {
      float e0 = __builtin_amdgcn_exp2f(sacc[qt][0]);
      float e1 = __builtin_amdgcn_exp2f(sacc[qt][1]);
      float e2 = __builtin_amdgcn_exp2f(sacc[qt][2]);
      float e3 = __builtin_amdgcn_exp2f(sacc[qt][3]);
      uint32 p01 = pkbf(e0, e1) & m01;
      uint32 p23 = pkbf(e2, e3) & m23;
      lsum[qt] += (__uint_as_float(p01 << 16) + __uint_as_float(p01 & 0xffff0000u))
                + (__uint_as_float(p23 << 16) + __uint_as_float(p23 & 0xffff0000u));
      oacc[qt] = __builtin_amdgcn_mfma_f32_16x16x32_bf16(mk8(p01, p23), vf, oacc[qt], 0, 0, 0);
    }
  }

  #pragma unroll
  for (int qt = 0; qt < 4; qt++) {
    float l = lsum[qt];
    l += __shfl_xor(l, 16);
    l += __shfl_xor(l, 32);
    lsum[qt] = 1.0f / fmaxf(l, 1e-30f);
  }
  if (w <= 60) {
    #pragma unroll
    for (int qt = 0; qt < 4; qt++) {
      #pragma unroll
      for (int r = 0; r < 4; r++) {
        int qloc = qt * 16 + quad * 4 + r;
        float invl = __shfl(lsum[qt], quad * 4 + r);
        if (qloc < 61) {
          size_t row = (size_t)b * S_ + w * 61 + qloc;
          o[row * 128 + hh * 16 + qcol] = f2bf(oacc[qt][r] * invl);
        }
      }
    }
  }
}

extern "C" void kernel_launch(void* const* d_in, const int* in_sizes, int n_in,
                              void* d_out, int out_size, void* d_ws, size_t ws_size,
                              hipStream_t stream) {
  const float* x      = (const float*)d_in[0];
  const float* conv_w = (const float*)d_in[1];
  const float* conv_b = (const float*)d_in[2];
  const float* lt_w   = (const float*)d_in[3];
  const float* lt_b   = (const float*)d_in[4];
  const float* pos    = (const float*)d_in[5];
  const float* ln1_s  = (const float*)d_in[6];
  const float* ln1_b  = (const float*)d_in[7];
  const float* wq     = (const float*)d_in[8];
  const float* wk     = (const float*)d_in[9];
  const float* wv     = (const float*)d_in[10];
  const float* wo     = (const float*)d_in[11];
  const float* wo_b   = (const float*)d_in[12];
  const float* ln2_s  = (const float*)d_in[13];
  const float* ln2_b  = (const float*)d_in[14];
  const float* ff_w1  = (const float*)d_in[15];
  const float* ff_b1  = (const float*)d_in[16];
  const float* ff_w2  = (const float*)d_in[17];
  const float* ff_b2  = (const float*)d_in[18];
  const float* pre_w1 = (const float*)d_in[19];
  const float* pre_b1 = (const float*)d_in[20];
  const float* pre_w2 = (const float*)d_in[21];
  const float* pre_b2 = (const float*)d_in[22];

  char* ws = (char*)d_ws;
  const size_t SZ_HB  = (size_t)BS_ * 128 * 2;   // bf16 residual stream
  const size_t SZ_QKV = (size_t)BS_ * 384 * 2;
  const size_t SZ_O   = (size_t)BS_ * 128 * 2;
  ushort16* h    = (ushort16*)ws;
  ushort16* hn   = (ushort16*)(ws + SZ_HB);
  ushort16* qkvb = (ushort16*)(ws + 2 * SZ_HB);                 // also p, t
  ushort16* ob   = (ushort16*)(ws + 2 * SZ_HB + SZ_QKV);        // also X
  char*     wsw  = ws + 2 * SZ_HB + SZ_QKV + SZ_O;
  ushort16* qkv_t = (ushort16*)(wsw);
  ushort16* wo_t  = qkv_t + 196608;
  ushort16* w1_t  = wo_t  + 65536;
  ushort16* w2_t  = w1_t  + 262144;
  ushort16* lt_t  = w2_t  + 262144;
  ushort16* pw1_t = lt_t  + 8192;
  ushort16* wc_t  = pw1_t + 16384;
  float*    cb_pad = (float*)(wc_t + 4096);
  ushort16* X  = ob;        // im2col patches [BS][64] bf16
  ushort16* p  = qkvb;      // conv output (post-relu) [BS][64] bf16
  ushort16* t  = qkvb;      // FF intermediate [BS][512]

  prep_w<<<dim3(3185), 256, 0, stream>>>(wq, wk, wv, wo, ff_w1, ff_w2, lt_w, pre_w1,
                                         conv_w, conv_b,
                                         qkv_t, wo_t, w1_t, w2_t, lt_t, pw1_t, wc_t, cb_pad);
  im2col_k<<<dim3((BS_ * 64 + 255) / 256), 256, 0, stream>>>(x, X);

  const int MB = (BS_ + 127) / 128;  // 466
  // p = relu(X @ Wc^T + cb)
  gemm_bf16<E_RELU, 64, false><<<dim3(1, MB), 512, 0, stream>>>(X, 64, wc_t, 64, nullptr, p, 64,
                                                                cb_pad, nullptr, nullptr, nullptr, nullptr,
                                                                BS_, 64);
  // h = p @ lt_w + lt_b + pos ; hn = LN1_0(h)
  gemm_bf16<E_H0LN, 64, false><<<dim3(1, MB), 512, 0, stream>>>(p, 64, lt_t, 64, h, hn, 128,
                                                                lt_b, pos, ln1_s, ln1_b, nullptr, BS_, 128);

  for (int l = 0; l < 4; l++) {
    gemm_bf16<E_QKV, 128, true><<<dim3(3, MB), 512, 0, stream>>>(hn, 128, qkv_t + (size_t)l * 49152, 128,
                                                                 nullptr, qkvb, 384, nullptr, nullptr,
                                                                 nullptr, nullptr, nullptr, BS_, 384);
    attn4<<<dim3(2048), 256, 0, stream>>>(qkvb, ob);
    // h += o @ wo + wo_b ; hn = LN2_l(h)
    gemm_bf16<E_RESLN, 128, false><<<dim3(1, MB), 512, 0, stream>>>(ob, 128, wo_t + (size_t)l * 16384, 128,
                                                                    h, hn, 128, wo_b + l * 128, nullptr,
                                                                    ln2_s + l * 128, ln2_b + l * 128, nullptr,
                                                                    BS_, 128);
    gemm_bf16<E_GELU, 128, false><<<dim3(4, MB), 512, 0, stream>>>(hn, 128, w1_t + (size_t)l * 65536, 128,
                                                                   nullptr, t, 512, ff_b1 + l * 512, nullptr,
                                                                   nullptr, nullptr, nullptr, BS_, 512);
    if (l < 3) {
      // h += t @ w2 + b2 ; hn = LN1_{l+1}(h)
      gemm_bf16<E_RESLN, 512, false><<<dim3(1, MB), 512, 0, stream>>>(t, 512, w2_t + (size_t)l * 65536, 512,
                                                                      h, hn, 128, ff_b2 + l * 128, nullptr,
                                                                      ln1_s + (l + 1) * 128, ln1_b + (l + 1) * 128,
                                                                      nullptr, BS_, 128);
    } else {  // final: h += t @ w2 + b2 (bf16 h, no LN)
      gemm_bf16<E_RESBF, 512, false><<<dim3(1, MB), 512, 0, stream>>>(t, 512, w2_t + (size_t)l * 65536, 512,
                                                                      h, nullptr, 128, ff_b2 + l * 128, nullptr,
                                                                      nullptr, nullptr, nullptr, BS_, 128);
    }
  }
  // fused head: out = relu(h @ pre_w1 + pre_b1) @ pre_w2 + pre_b2
  gemm_bf16<E_HEAD, 128, false><<<dim3(1, MB), 512, 0, stream>>>(h, 128, pw1_t, 128,
                                                                 nullptr, nullptr, 128, pre_b1, nullptr,
                                                                 pre_w2, pre_b2, (float*)d_out, BS_, 128);
}